// Round 3
// baseline (738.048 us; speedup 1.0000x reference)
//
#include <hip/hip_runtime.h>
#include <cstdint>
#include <cstddef>

// Problem constants
#define B_SZ      2
#define S_LEN     2048
#define HID_DIM   1024
#define N_HEAD    16
#define D_HEAD    64
#define INNER_DIM 1024

// scores = (s + bias)/8 + mask, softmax in exp2 space.
// 0.125*log2(e) folded into Q at projection; fused = bias*C1 + mask*C2.
#define C1 0.18033688011112042f    /* 0.125 * log2(e) */
#define C2 1.44269504088896340736f /* log2(e) */

typedef __attribute__((ext_vector_type(8))) short bf16x8;   // 8 x bf16 (4 VGPRs)
typedef __attribute__((ext_vector_type(4))) float f32x4;    // MFMA 16x16 C/D

__device__ __forceinline__ unsigned short f2bf(float f) {
  unsigned int u = __float_as_uint(f);
  u += 0x7fffu + ((u >> 16) & 1u);
  return (unsigned short)(u >> 16);
}
__device__ __forceinline__ float bf2f(unsigned short u) {
  return __uint_as_float(((unsigned int)u) << 16);
}

// async global->LDS, 16B per lane; dest = wave-uniform base + lane*16
__device__ __forceinline__ void gload_lds16(const void* g, void* l) {
  __builtin_amdgcn_global_load_lds((const __attribute__((address_space(1))) void*)g,
                                   (__attribute__((address_space(3))) void*)l,
                                   16, 0, 0);
}

// ---------------------------------------------------------------- cast fp32->bf16 (x3)
__global__ void cast3_kernel(const float* __restrict__ i0, const float* __restrict__ i1,
                             const float* __restrict__ i2,
                             unsigned short* __restrict__ o0, unsigned short* __restrict__ o1,
                             unsigned short* __restrict__ o2, int n4) {
  int z = blockIdx.y;
  const float* in = (z == 0) ? i0 : (z == 1) ? i1 : i2;
  unsigned short* out = (z == 0) ? o0 : (z == 1) ? o1 : o2;
  int i = blockIdx.x * blockDim.x + threadIdx.x;
  if (i < n4) {
    float4 v = ((const float4*)in)[i];
    ushort4 o;
    o.x = f2bf(v.x); o.y = f2bf(v.y); o.z = f2bf(v.z); o.w = f2bf(v.w);
    ((ushort4*)out)[i] = o;
  }
}

// --------------------------- transpose + cast all four 1024x1024 weights in one dispatch
__global__ void transpose4_kernel(const float* __restrict__ w0, const float* __restrict__ w1,
                                  const float* __restrict__ w2, const float* __restrict__ w3,
                                  unsigned short* __restrict__ o0, unsigned short* __restrict__ o1,
                                  unsigned short* __restrict__ o2, unsigned short* __restrict__ o3) {
  __shared__ float tile[32][33];
  int z = blockIdx.z;
  const float* in = (z == 0) ? w0 : (z == 1) ? w1 : (z == 2) ? w2 : w3;
  unsigned short* out = (z == 0) ? o0 : (z == 1) ? o1 : (z == 2) ? o2 : o3;
  const int N = 1024;
  int bx = blockIdx.x * 32;
  int by = blockIdx.y * 32;
  int tx = threadIdx.x & 31;
  int ty = threadIdx.x >> 5;
#pragma unroll
  for (int i = 0; i < 32; i += 8)
    tile[ty + i][tx] = in[(size_t)(by + ty + i) * N + bx + tx];
  __syncthreads();
#pragma unroll
  for (int i = 0; i < 32; i += 8)
    out[(size_t)(bx + ty + i) * N + by + tx] = f2bf(tile[tx][ty + i]);
}

// ---------------------------------------------------------------- GEMM (m97 structure)
// C = A @ Bt^T + bias.  A: [M][1024] bf16.  Bt: [N][1024] bf16 (pre-transposed).
// Tile 128x128x64, 256 thr = 4 waves (2x2), wave computes 64x64 (acc 4x4).
// LDS XOR-swizzle: 16B segment stored at seg ^ (row & 7)  (2-way conflicts free).
// MODE 0: bf16 out row-major, value (acc+bias)*scale
// MODE 1: bf16 out transposed to [B][H][D][S]   (for V)
// MODE 2: fp32 out row-major
template <int MODE>
__global__ __launch_bounds__(256, 2)
void gemm128_kernel(const unsigned short* __restrict__ A,
                    const unsigned short* __restrict__ Bt,
                    const float* __restrict__ bias,
                    void* __restrict__ out, float scale) {
  constexpr int K = 1024;
  __shared__ unsigned short Asm[128 * 64];
  __shared__ unsigned short Bsm[128 * 64];

  const int tid = threadIdx.x;
  const int lane = tid & 63;
  const int w = tid >> 6;
  const int wm = w & 1;
  const int wn = w >> 1;
  const int c = lane & 15;
  const int g = lane >> 4;
  const int m0 = blockIdx.x * 128;
  const int n0 = blockIdx.y * 128;

  f32x4 acc[4][4];
  f32x4 zero = {0.f, 0.f, 0.f, 0.f};
#pragma unroll
  for (int mt = 0; mt < 4; ++mt)
#pragma unroll
    for (int nt = 0; nt < 4; ++nt) acc[mt][nt] = zero;

  for (int kk = 0; kk < K / 64; ++kk) {
    __syncthreads();
    const int k0 = kk * 64;
#pragma unroll
    for (int it = 0; it < 4; ++it) {     // A: 128 rows x 8 segs = 1024 slots
      int slot = it * 256 + tid;
      int r = slot >> 3, sp = slot & 7, seg = sp ^ (r & 7);
      gload_lds16(A + (size_t)(m0 + r) * K + k0 + seg * 8,
                  (char*)Asm + (it * 256 + w * 64) * 16);
    }
#pragma unroll
    for (int it = 0; it < 4; ++it) {     // B: 128 rows
      int slot = it * 256 + tid;
      int r = slot >> 3, sp = slot & 7, seg = sp ^ (r & 7);
      gload_lds16(Bt + (size_t)(n0 + r) * K + k0 + seg * 8,
                  (char*)Bsm + (it * 256 + w * 64) * 16);
    }
    __syncthreads();

#pragma unroll
    for (int ks = 0; ks < 2; ++ks) {
      bf16x8 aF[4], bF[4];
#pragma unroll
      for (int mt = 0; mt < 4; ++mt) {
        int r = wm * 64 + mt * 16 + c;
        int seg = (ks * 4 + g) ^ (r & 7);
        aF[mt] = *(const bf16x8*)((const char*)Asm + r * 128 + seg * 16);
      }
#pragma unroll
      for (int nt = 0; nt < 4; ++nt) {
        int r = wn * 64 + nt * 16 + c;
        int seg = (ks * 4 + g) ^ (r & 7);
        bF[nt] = *(const bf16x8*)((const char*)Bsm + r * 128 + seg * 16);
      }
#pragma unroll
      for (int mt = 0; mt < 4; ++mt)
#pragma unroll
        for (int nt = 0; nt < 4; ++nt)
          acc[mt][nt] = __builtin_amdgcn_mfma_f32_16x16x32_bf16(aF[mt], bF[nt], acc[mt][nt], 0, 0, 0);
    }
  }

#pragma unroll
  for (int nt = 0; nt < 4; ++nt) {
    int n_g = n0 + wn * 64 + nt * 16 + c;
    float bvv = bias[n_g];
#pragma unroll
    for (int mt = 0; mt < 4; ++mt) {
      int m_base = m0 + wm * 64 + mt * 16 + g * 4;
      if (MODE == 0) {
        unsigned short* o = (unsigned short*)out;
#pragma unroll
        for (int r = 0; r < 4; ++r)
          o[(size_t)(m_base + r) * INNER_DIM + n_g] = f2bf((acc[mt][nt][r] + bvv) * scale);
      } else if (MODE == 1) {
        int b = m_base >> 11;
        int s = m_base & 2047;
        int hh = n_g >> 6;
        int d = n_g & 63;
        ushort4 pk;
        pk.x = f2bf(acc[mt][nt][0] + bvv);
        pk.y = f2bf(acc[mt][nt][1] + bvv);
        pk.z = f2bf(acc[mt][nt][2] + bvv);
        pk.w = f2bf(acc[mt][nt][3] + bvv);
        *(ushort4*)((unsigned short*)out +
                    ((size_t)((b * N_HEAD + hh) * D_HEAD + d)) * S_LEN + s) = pk;
      } else {
        float* o = (float*)out;
#pragma unroll
        for (int r = 0; r < 4; ++r)
          o[(size_t)(m_base + r) * HID_DIM + n_g] = acc[mt][nt][r] + bvv;
      }
    }
  }
}

// ---------------------------------------------------------------- flash attention, dual-batch
// block = (q-tile 64, head); 256 thr = 4 waves, wave w owns q rows [w*16, w*16+16).
// Both batches processed per block -> bias fetched ONCE device-wide.
// Qp,Kp: [B*S][1024] bf16 (Q pre-scaled by C1).  Vp: [B][H][D][S] bf16.
// LDS 80 KB -> 2 blocks/CU.  bias/mask fp32 loads prefetched one kv-iter ahead.
__global__ __launch_bounds__(256, 2)
void attn_kernel(const unsigned short* __restrict__ Qp,
                 const unsigned short* __restrict__ Kp,
                 const unsigned short* __restrict__ Vp,
                 const float* __restrict__ bias,   // [1][H][S][S]
                 const float* __restrict__ mask,   // [B][1][S][S]
                 unsigned short* __restrict__ Osm) {
  __shared__ unsigned short Ksm[2 * 128 * 64];   // per-batch [kv][d], NSEG8 swizzle, 32 KB
  __shared__ unsigned short Vsm[2 * 64 * 128];   // per-batch [d][kv], NSEG16 swizzle, 32 KB
  __shared__ unsigned short Psm[4 * 16 * 128];   // wave-private 16x128, 16 KB

  const int tid = threadIdx.x;
  const int lane = tid & 63;
  const int w = tid >> 6;           // wave 0..3
  const int c = lane & 15;
  const int g = lane >> 4;
  const int q0 = blockIdx.x * 64;
  const int h = blockIdx.y;

  char* KsmB = (char*)Ksm;
  char* VsmB = (char*)Vsm;
  char* Pw = (char*)Psm + w * 4096;    // 16 rows x 256 B

  // Q fragments, both batches (A-layout: m=c, k=g*8+j)
  bf16x8 qF[2][2];
#pragma unroll
  for (int b2 = 0; b2 < 2; ++b2) {
    size_t row = (size_t)(b2 * S_LEN + q0 + w * 16 + c);
#pragma unroll
    for (int ks = 0; ks < 2; ++ks)
      qF[b2][ks] = *(const bf16x8*)(Qp + row * INNER_DIM + h * D_HEAD + ks * 32 + g * 8);
  }

  // coalesced bias/mask: lane covers (row lrow, 4 cols at lcol*4)
  const int lrow = lane >> 5;           // 0..1
  const int lcol = lane & 31;
  const float* bias_p  = bias + ((size_t)h * S_LEN + q0 + w * 16 + lrow) * S_LEN + lcol * 4;
  const float* mask_p0 = mask + ((size_t)(q0 + w * 16 + lrow)) * S_LEN + lcol * 4;
  const float* mask_p1 = mask_p0 + (size_t)S_LEN * S_LEN;

  float4 pb[8], pm0[8], pm1[8];        // pending (next-iter) bias/mask
#pragma unroll
  for (int p = 0; p < 8; ++p) {        // prologue: j=0
    pb[p]  = *(const float4*)(bias_p  + (size_t)(p * 2) * S_LEN);
    pm0[p] = *(const float4*)(mask_p0 + (size_t)(p * 2) * S_LEN);
    pm1[p] = *(const float4*)(mask_p1 + (size_t)(p * 2) * S_LEN);
  }

  float m_run[2][4], l_run[2][4];
  f32x4 oacc[2][4];
  f32x4 zero = {0.f, 0.f, 0.f, 0.f};
#pragma unroll
  for (int b2 = 0; b2 < 2; ++b2) {
#pragma unroll
    for (int r = 0; r < 4; ++r) { m_run[b2][r] = -1e30f; l_run[b2][r] = 0.f; }
#pragma unroll
    for (int dt = 0; dt < 4; ++dt) oacc[b2][dt] = zero;
  }

  for (int j = 0; j < S_LEN / 128; ++j) {
    // fused0 = bias*C1 + mask0*C2 -> Pw (wave-private; prev-iter P reads same-wave ordered)
#pragma unroll
    for (int p = 0; p < 8; ++p) {
      ushort4 fo;
      fo.x = f2bf(pb[p].x * C1 + pm0[p].x * C2);
      fo.y = f2bf(pb[p].y * C1 + pm0[p].y * C2);
      fo.z = f2bf(pb[p].z * C1 + pm0[p].z * C2);
      fo.w = f2bf(pb[p].w * C1 + pm0[p].w * C2);
      *(ushort4*)(Pw + (p * 2 + lrow) * 256 + lcol * 8) = fo;
    }
    __syncthreads();                 // all waves done reading prev K/V

    // stage K,V for both batches: 4 tiles x 16 KB, 4 DMA instr each
#pragma unroll
    for (int b2 = 0; b2 < 2; ++b2) {
#pragma unroll
      for (int it = 0; it < 4; ++it) {
        int slot = it * 256 + tid;
        int r = slot >> 3, sp = slot & 7, seg = sp ^ (r & 7);
        gload_lds16(Kp + (size_t)(b2 * S_LEN + j * 128 + r) * INNER_DIM + h * D_HEAD + seg * 8,
                    KsmB + b2 * 16384 + (it * 256 + w * 64) * 16);
      }
#pragma unroll
      for (int it = 0; it < 4; ++it) {
        int slot = it * 256 + tid;
        int r = slot >> 4, sp = slot & 15, seg = sp ^ (r & 15);
        gload_lds16(Vp + ((size_t)((b2 * N_HEAD + h) * D_HEAD + r)) * S_LEN + j * 128 + seg * 8,
                    VsmB + b2 * 16384 + (it * 256 + w * 64) * 16);
      }
    }
    __syncthreads();                 // staged (drains vmcnt)

#pragma unroll
    for (int b2 = 0; b2 < 2; ++b2) {
      if (b2 == 1) {
        // fused1 -> Pw (P0 reads done, same wave)
#pragma unroll
        for (int p = 0; p < 8; ++p) {
          ushort4 fo;
          fo.x = f2bf(pb[p].x * C1 + pm1[p].x * C2);
          fo.y = f2bf(pb[p].y * C1 + pm1[p].y * C2);
          fo.z = f2bf(pb[p].z * C1 + pm1[p].z * C2);
          fo.w = f2bf(pb[p].w * C1 + pm1[p].w * C2);
          *(ushort4*)(Pw + (p * 2 + lrow) * 256 + lcol * 8) = fo;
        }
        // prefetch next iter's bias/mask (issued mid-compute, drained next barrier)
        if (j < S_LEN / 128 - 1) {
          int off = (j + 1) * 128;
#pragma unroll
          for (int p = 0; p < 8; ++p) {
            pb[p]  = *(const float4*)(bias_p  + (size_t)(p * 2) * S_LEN + off);
            pm0[p] = *(const float4*)(mask_p0 + (size_t)(p * 2) * S_LEN + off);
            pm1[p] = *(const float4*)(mask_p1 + (size_t)(p * 2) * S_LEN + off);
          }
        }
      }

      // S = Q K^T  (q rows g*4+r local, kv cols nt*16+c)
      f32x4 sAcc[8];
#pragma unroll
      for (int nt = 0; nt < 8; ++nt) sAcc[nt] = zero;
#pragma unroll
      for (int ks = 0; ks < 2; ++ks)
#pragma unroll
        for (int nt = 0; nt < 8; ++nt) {
          int r = nt * 16 + c;
          int seg = (ks * 4 + g) ^ (r & 7);
          bf16x8 kF = *(const bf16x8*)(KsmB + b2 * 16384 + r * 128 + seg * 16);
          sAcc[nt] = __builtin_amdgcn_mfma_f32_16x16x32_bf16(qF[b2][ks], kF, sAcc[nt], 0, 0, 0);
        }

      // add fused bias+mask (read back from wave-private LDS)
#pragma unroll
      for (int nt = 0; nt < 8; ++nt)
#pragma unroll
        for (int r = 0; r < 4; ++r)
          sAcc[nt][r] += bf2f(*(const unsigned short*)(Pw + (g * 4 + r) * 256 + (nt * 16 + c) * 2));

      // online softmax (exp2 space)
#pragma unroll
      for (int r = 0; r < 4; ++r) {
        float mx = sAcc[0][r];
#pragma unroll
        for (int nt = 1; nt < 8; ++nt) mx = fmaxf(mx, sAcc[nt][r]);
        mx = fmaxf(mx, __shfl_xor(mx, 1));
        mx = fmaxf(mx, __shfl_xor(mx, 2));
        mx = fmaxf(mx, __shfl_xor(mx, 4));
        mx = fmaxf(mx, __shfl_xor(mx, 8));
        float mnew = fmaxf(m_run[b2][r], mx);
        float alpha = __builtin_amdgcn_exp2f(m_run[b2][r] - mnew);
        m_run[b2][r] = mnew;
        float ssum = 0.f;
#pragma unroll
        for (int nt = 0; nt < 8; ++nt) {
          float pv = __builtin_amdgcn_exp2f(sAcc[nt][r] - mnew);
          sAcc[nt][r] = pv;
          ssum += pv;
        }
        ssum += __shfl_xor(ssum, 1);
        ssum += __shfl_xor(ssum, 2);
        ssum += __shfl_xor(ssum, 4);
        ssum += __shfl_xor(ssum, 8);
        l_run[b2][r] = l_run[b2][r] * alpha + ssum;
#pragma unroll
        for (int dt = 0; dt < 4; ++dt) oacc[b2][dt][r] *= alpha;
      }

      // P -> Pw (C-layout -> A-layout), NSEG16 swizzle
#pragma unroll
      for (int nt = 0; nt < 8; ++nt)
#pragma unroll
        for (int r = 0; r < 4; ++r) {
          int row_l = g * 4 + r;
          int kv = nt * 16 + c;
          int seg = (kv >> 3) ^ row_l;
          *(unsigned short*)(Pw + row_l * 256 + seg * 16 + (kv & 7) * 2) = f2bf(sAcc[nt][r]);
        }

      // O += P @ V
#pragma unroll
      for (int ks = 0; ks < 4; ++ks) {
        int segP = (ks * 4 + g) ^ c;
        bf16x8 aP = *(const bf16x8*)(Pw + c * 256 + segP * 16);
#pragma unroll
        for (int dt = 0; dt < 4; ++dt) {
          int dr = dt * 16 + c;
          int segV = (ks * 4 + g) ^ (dr & 15);
          bf16x8 vF = *(const bf16x8*)(VsmB + b2 * 16384 + dr * 256 + segV * 16);
          oacc[b2][dt] = __builtin_amdgcn_mfma_f32_16x16x32_bf16(aP, vF, oacc[b2][dt], 0, 0, 0);
        }
      }
    }
  }

  // normalize + store bf16 [B*S][INNER]
#pragma unroll
  for (int b2 = 0; b2 < 2; ++b2)
#pragma unroll
    for (int r = 0; r < 4; ++r) {
      float inv = 1.f / l_run[b2][r];
      int qg = q0 + w * 16 + g * 4 + r;
#pragma unroll
      for (int dt = 0; dt < 4; ++dt)
        Osm[(size_t)(b2 * S_LEN + qg) * INNER_DIM + h * D_HEAD + dt * 16 + c] =
            f2bf(oacc[b2][dt][r] * inv);
    }
}

// ---------------------------------------------------------------- launch
extern "C" void kernel_launch(void* const* d_in, const int* in_sizes, int n_in,
                              void* d_out, int out_size, void* d_ws, size_t ws_size,
                              hipStream_t stream) {
  const float* query = (const float*)d_in[0];
  const float* key   = (const float*)d_in[1];
  const float* value = (const float*)d_in[2];
  const float* mask  = (const float*)d_in[3];
  const float* bias  = (const float*)d_in[4];
  const float* Wq = (const float*)d_in[5];
  const float* bq = (const float*)d_in[6];
  const float* Wk = (const float*)d_in[7];
  const float* bk = (const float*)d_in[8];
  const float* Wv = (const float*)d_in[9];
  const float* bv = (const float*)d_in[10];
  const float* Wo = (const float*)d_in[11];
  const float* bo = (const float*)d_in[12];

  const size_t NTOK   = (size_t)B_SZ * S_LEN;       // 4096
  const size_t SZ_ACT = NTOK * INNER_DIM;
  const size_t SZ_W   = (size_t)HID_DIM * INNER_DIM;

  unsigned short* ws  = (unsigned short*)d_ws;
  unsigned short* qb  = ws;
  unsigned short* kb  = qb + SZ_ACT;
  unsigned short* vb  = kb + SZ_ACT;
  unsigned short* Wqt = vb + SZ_ACT;
  unsigned short* Wkt = Wqt + SZ_W;
  unsigned short* Wvt = Wkt + SZ_W;
  unsigned short* Wot = Wvt + SZ_W;
  unsigned short* Qp  = Wot + SZ_W;
  unsigned short* Kp  = Qp + SZ_ACT;
  unsigned short* Vp  = Kp + SZ_ACT;                // [B][H][D][S]
  unsigned short* Ob  = Vp + SZ_ACT;

  int n4 = (int)(SZ_ACT / 4);
  dim3 cgrid((n4 + 255) / 256, 3);
  cast3_kernel<<<cgrid, 256, 0, stream>>>(query, key, value, qb, kb, vb, n4);

  dim3 tgrid(32, 32, 4);
  transpose4_kernel<<<tgrid, 256, 0, stream>>>(Wq, Wk, Wv, Wo, Wqt, Wkt, Wvt, Wot);

  dim3 ggrid(NTOK / 128, INNER_DIM / 128);          // (32, 8)
  gemm128_kernel<0><<<ggrid, 256, 0, stream>>>(qb, Wqt, bq, Qp, C1);   // Q (pre-scaled)
  gemm128_kernel<0><<<ggrid, 256, 0, stream>>>(kb, Wkt, bk, Kp, 1.0f); // K
  gemm128_kernel<1><<<ggrid, 256, 0, stream>>>(vb, Wvt, bv, Vp, 1.0f); // V (transposed)

  dim3 agrid(S_LEN / 64, N_HEAD);                   // (32, 16) = 512 blocks
  attn_kernel<<<agrid, 256, 0, stream>>>(Qp, Kp, Vp, bias, mask, Ob);

  gemm128_kernel<2><<<ggrid, 256, 0, stream>>>(Ob, Wot, bo, d_out, 1.0f); // out proj
}